// Round 7
// baseline (113.368 us; speedup 1.0000x reference)
//
#include <hip/hip_runtime.h>

#define T 16
#define E 30
#define H 50
#define VOCAB 100
#define ROWS 208        // 13 row-tiles of 16; rows interleaved r = 4*unit + gate
#define K1 1.44269504089f   // log2(e)
#define K2 2.88539008178f   // 2*log2(e)

typedef _Float16 v8hf __attribute__((ext_vector_type(8)));
typedef float v4f __attribute__((ext_vector_type(4)));

extern "C" __device__ float __ocml_native_exp2_f32(float);
__device__ __forceinline__ float e2(float x)   { return __ocml_native_exp2_f32(x); }
__device__ __forceinline__ float rcpf(float x) { return __builtin_amdgcn_rcpf(x); }

// tbl[dir][v][r], r = 4*unit + gate (i,f,g,o), orig row = gate*50+unit.
// Rows pre-scaled: i/f/o by -log2e (sigmoid = rcp(1+exp2(x))), g by 2*log2e.
__global__ void build_tbl(const float* __restrict__ emb,
                          const float* __restrict__ w_ih,
                          const float* __restrict__ b_ih,
                          const float* __restrict__ b_hh,
                          float* __restrict__ tbl) {
    int idx = blockIdx.x * blockDim.x + threadIdx.x;
    if (idx >= VOCAB * ROWS) return;
    int v = idx / ROWS, r = idx % ROWS;
    float s = 0.f;
    if (r < 4 * H) {
        int orig = (r & 3) * H + (r >> 2);
        s = b_ih[orig] + b_hh[orig];
        const float* er = emb + v * E;
        const float* wr = w_ih + orig * E;
#pragma unroll
        for (int e = 0; e < E; ++e) s += er[e] * wr[e];
        s *= ((r & 3) == 2) ? K2 : -K1;
    }
    tbl[idx] = s;
}

// hbuf layout (fp16): [buf][hi/lo][seq16][slot56]
#define HL_STRIDE  (16 * 56)       // 896 halves
#define BUF_STRIDE (2 * 16 * 56)   // 1792 halves

// One wave handles row-tiles [RT0, RT0+NT) of its block's 16-seq group.
template<int RT0, int NT>
__device__ __forceinline__ void run_part(
    const float* __restrict__ whh, const float* __restrict__ tb,
    const int* __restrict__ myids, _Float16* __restrict__ hb0,
    float* __restrict__ out, int seq, int dir, int capt, int l15, int lg)
{
    // A-fragments (pre-scaled fp16 W) resident for the whole kernel.
    v8hf afrag[NT][2];
#pragma unroll
    for (int i = 0; i < NT; ++i) {
        const int r = (RT0 + i) * 16 + l15;
        const bool vr = (r < 4 * H);
        const int orig = vr ? ((r & 3) * H + (r >> 2)) : 0;
        const float sc = ((r & 3) == 2) ? K2 : -K1;
#pragma unroll
        for (int kh = 0; kh < 2; ++kh) {
            v8hf af;
#pragma unroll
            for (int j = 0; j < 8; ++j) {
                const int k = kh * 32 + lg * 8 + j;
                af[j] = (_Float16)((vr && k < H) ? sc * whh[orig * H + k] : 0.f);
            }
            afrag[i][kh] = af;
        }
    }
    float cs[NT], hcap[NT];
#pragma unroll
    for (int i = 0; i < NT; ++i) { cs[i] = 0.f; hcap[i] = 0.f; }

    const int roff = l15 * 56 + lg * 8;        // B-frag read offset (halves)
    const int woff = l15 * 56 + RT0 * 4 + lg;  // h write offset (halves)

    int id_next = myids[dir ? (T - 1) : 0];

    for (int t = 0; t < T; ++t) {
        const int cur = t & 1, nxt = cur ^ 1;
        const int id = id_next;
        if (t < T - 1) id_next = myids[dir ? (T - 2 - t) : (t + 1)];
        const float* __restrict__ trow = tb + id * ROWS;

        const _Float16* rb = hb0 + cur * BUF_STRIDE;
        v8hf bh0 = *(const v8hf*)(rb + roff);
        v8hf bh1 = *(const v8hf*)(rb + roff + 32);
        v8hf bl0 = *(const v8hf*)(rb + HL_STRIDE + roff);
        v8hf bl1 = *(const v8hf*)(rb + HL_STRIDE + roff + 32);

        _Float16* wb = hb0 + nxt * BUF_STRIDE + woff;
        const bool cap = (t == capt);

#pragma unroll
        for (int i = 0; i < NT; ++i) {
            const int rt = RT0 + i;
            v4f c = *(const v4f*)(trow + rt * 16 + lg * 4);
            c = __builtin_amdgcn_mfma_f32_16x16x32_f16(afrag[i][0], bh0, c, 0, 0, 0);
            c = __builtin_amdgcn_mfma_f32_16x16x32_f16(afrag[i][1], bh1, c, 0, 0, 0);
            c = __builtin_amdgcn_mfma_f32_16x16x32_f16(afrag[i][0], bl0, c, 0, 0, 0);
            c = __builtin_amdgcn_mfma_f32_16x16x32_f16(afrag[i][1], bl1, c, 0, 0, 0);

            // gates arrive pre-scaled: sigm = rcp(1+exp2(x)), tanh from exp2
            float i_ = rcpf(1.f + e2(c[0]));
            float f_ = rcpf(1.f + e2(c[1]));
            float eg = e2(c[2]);
            float g_ = (eg - 1.f) * rcpf(eg + 1.f);
            float o_ = rcpf(1.f + e2(c[3]));
            cs[i] = fmaf(f_, cs[i], (i_ * g_) * K2);   // c kept in 2*log2e domain
            float ec = e2(cs[i]);
            float th = (ec - 1.f) * rcpf(ec + 1.f);
            float hn = o_ * th;

            if (rt != 12 || lg < 2) {                  // folds except pad tile
                _Float16 hi = (_Float16)hn;
                wb[i * 4] = hi;
                wb[HL_STRIDE + i * 4] = (_Float16)(hn - (float)hi);
                hcap[i] = cap ? hn : hcap[i];
            }
        }
        __syncthreads();   // h(t) visible to all 4 waves before step t+1
    }

#pragma unroll
    for (int i = 0; i < NT; ++i) {
        const int u = (RT0 + i) * 4 + lg;
        if (u < H) out[seq * 100 + dir * H + u] = hcap[i];
    }
}

__global__ __launch_bounds__(256, 6) void lstm_mfma(
    const int* __restrict__ ids,     // [NSEQ, T]
    const float* __restrict__ tbl,   // [2][VOCAB][ROWS]
    const float* __restrict__ whh_f, // [200][50]
    const float* __restrict__ whh_r, // [200][50]
    float* __restrict__ out)         // [NSEQ, 100]
{
    __shared__ _Float16 hbuf[2][2][16][56];   // 7168 B, one 16-seq group

    const int tid = threadIdx.x;
    const int lane = tid & 63;
    const int wave = tid >> 6;       // row-quarter: {0-2},{3-5},{6-8},{9-12}
    const int l15 = lane & 15;       // seq within group / C col
    const int lg = lane >> 4;        // k-/row-group
    const int b = blockIdx.x;
    const int dir = b >> 10;         // 2048 blocks: 0..1023 fwd, 1024..2047 rev
    const int seq = (b & 1023) * 16 + l15;

    const float* __restrict__ whh = dir ? whh_r : whh_f;
    const float* __restrict__ tb  = tbl + dir * (VOCAB * ROWS);
    const int* __restrict__ myids = ids + seq * T;

    // zero both h double-buffers (incl. K-pad slots 50..55)
    {
        int* hz = (int*)&hbuf[0][0][0][0];
#pragma unroll
        for (int i = tid; i < (int)(sizeof(hbuf) / 4); i += 256) hz[i] = 0;
    }

    // ragged length -> capture step (per lane's own sequence)
    int capt;
    {
        const int4* q = (const int4*)myids;
        int4 a0 = q[0], a1 = q[1], a2 = q[2], a3 = q[3];
        int len = (a0.x != 0) + (a0.y != 0) + (a0.z != 0) + (a0.w != 0)
                + (a1.x != 0) + (a1.y != 0) + (a1.z != 0) + (a1.w != 0)
                + (a2.x != 0) + (a2.y != 0) + (a2.z != 0) + (a2.w != 0)
                + (a3.x != 0) + (a3.y != 0) + (a3.z != 0) + (a3.w != 0);
        capt = dir ? (T - 1) : ((len > 1) ? (len - 1) : 0);
    }

    __syncthreads();   // hbuf zeroed

    _Float16* hb0 = &hbuf[0][0][0][0];
    if      (wave == 0) run_part<0, 3>(whh, tb, myids, hb0, out, seq, dir, capt, l15, lg);
    else if (wave == 1) run_part<3, 3>(whh, tb, myids, hb0, out, seq, dir, capt, l15, lg);
    else if (wave == 2) run_part<6, 3>(whh, tb, myids, hb0, out, seq, dir, capt, l15, lg);
    else                run_part<9, 4>(whh, tb, myids, hb0, out, seq, dir, capt, l15, lg);
}

extern "C" void kernel_launch(void* const* d_in, const int* in_sizes, int n_in,
                              void* d_out, int out_size, void* d_ws, size_t ws_size,
                              hipStream_t stream) {
    const int*   char_ids = (const int*)d_in[0];
    const float* emb      = (const float*)d_in[1];
    const float* w_ih_f   = (const float*)d_in[2];
    const float* w_hh_f   = (const float*)d_in[3];
    const float* b_ih_f   = (const float*)d_in[4];
    const float* b_hh_f   = (const float*)d_in[5];
    const float* w_ih_r   = (const float*)d_in[6];
    const float* w_hh_r   = (const float*)d_in[7];
    const float* b_ih_r   = (const float*)d_in[8];
    const float* b_hh_r   = (const float*)d_in[9];
    float* out = (float*)d_out;
    float* tbl = (float*)d_ws; // [2][VOCAB][ROWS] f32 = 166.4 KB

    const int nt = VOCAB * ROWS; // 20800
    build_tbl<<<(nt + 255) / 256, 256, 0, stream>>>(emb, w_ih_f, b_ih_f, b_hh_f, tbl);
    build_tbl<<<(nt + 255) / 256, 256, 0, stream>>>(emb, w_ih_r, b_ih_r, b_hh_r, tbl + nt);
    // 2048 blocks: 1024 per direction; block = one 16-seq group x 4 row-quarter waves
    lstm_mfma<<<2048, 256, 0, stream>>>(char_ids, tbl, w_hh_f, w_hh_r, out);
}

// Round 8
// 79.909 us; speedup vs baseline: 1.4187x; 1.4187x over previous
//
#include <hip/hip_runtime.h>

#define T 16
#define E 30
#define H 50
#define VOCAB 100
#define ROWS 208        // 13 row-tiles of 16; rows interleaved r = 4*unit + gate
#define K1 1.44269504089f   // log2(e)
#define K2 2.88539008178f   // 2*log2(e)

typedef _Float16 v8hf __attribute__((ext_vector_type(8)));
typedef float v4f __attribute__((ext_vector_type(4)));

extern "C" __device__ float __ocml_native_exp2_f32(float);
__device__ __forceinline__ float e2(float x)   { return __ocml_native_exp2_f32(x); }
__device__ __forceinline__ float rcpf(float x) { return __builtin_amdgcn_rcpf(x); }

// tbl[dir][v][r], r = 4*unit + gate (i,f,g,o), orig row = gate*50+unit.
// Rows pre-scaled: i/f/o by -log2e (sigmoid = rcp(1+exp2(x))), g by 2*log2e.
__global__ void build_tbl(const float* __restrict__ emb,
                          const float* __restrict__ w_ih,
                          const float* __restrict__ b_ih,
                          const float* __restrict__ b_hh,
                          float* __restrict__ tbl) {
    int idx = blockIdx.x * blockDim.x + threadIdx.x;
    if (idx >= VOCAB * ROWS) return;
    int v = idx / ROWS, r = idx % ROWS;
    float s = 0.f;
    if (r < 4 * H) {
        int orig = (r & 3) * H + (r >> 2);
        s = b_ih[orig] + b_hh[orig];
        const float* er = emb + v * E;
        const float* wr = w_ih + orig * E;
#pragma unroll
        for (int e = 0; e < E; ++e) s += er[e] * wr[e];
        s *= ((r & 3) == 2) ? K2 : -K1;
    }
    tbl[idx] = s;
}

// hbuf layout (fp16): [buf][seq16][slot56]
#define BUF_STRIDE (16 * 56)   // halves

// One wave handles row-tiles [RT0, RT0+NT) of its block's 16-seq group.
template<int RT0, int NT>
__device__ __forceinline__ void run_part(
    const float* __restrict__ whh, const float* __restrict__ tb,
    const int* __restrict__ myids, _Float16* __restrict__ hb0,
    float* __restrict__ out, int seq, int dir, int capt, int l15, int lg)
{
    // A-fragments (pre-scaled fp16 W) resident for the whole kernel.
    v8hf afrag[NT][2];
#pragma unroll
    for (int i = 0; i < NT; ++i) {
        const int r = (RT0 + i) * 16 + l15;
        const bool vr = (r < 4 * H);
        const int orig = vr ? ((r & 3) * H + (r >> 2)) : 0;
        const float sc = ((r & 3) == 2) ? K2 : -K1;
#pragma unroll
        for (int kh = 0; kh < 2; ++kh) {
            v8hf af;
#pragma unroll
            for (int j = 0; j < 8; ++j) {
                const int k = kh * 32 + lg * 8 + j;
                af[j] = (_Float16)((vr && k < H) ? sc * whh[orig * H + k] : 0.f);
            }
            afrag[i][kh] = af;
        }
    }
    float cs[NT], hcap[NT];
#pragma unroll
    for (int i = 0; i < NT; ++i) { cs[i] = 0.f; hcap[i] = 0.f; }

    const int roff = l15 * 56 + lg * 8;        // B-frag read offset (halves)
    const int woff = l15 * 56 + RT0 * 4 + lg;  // h write offset (halves)

    int id_next = myids[dir ? (T - 1) : 0];

    for (int t = 0; t < T; ++t) {
        const int cur = t & 1, nxt = cur ^ 1;
        const int id = id_next;
        if (t < T - 1) id_next = myids[dir ? (T - 2 - t) : (t + 1)];
        const float* __restrict__ trow = tb + id * ROWS;

        // B-fragments: previous step's h (plain fp16), double-buffered
        const _Float16* rb = hb0 + cur * BUF_STRIDE;
        v8hf bh0 = *(const v8hf*)(rb + roff);
        v8hf bh1 = *(const v8hf*)(rb + roff + 32);

        _Float16* wb = hb0 + nxt * BUF_STRIDE + woff;
        const bool cap = (t == capt);

#pragma unroll
        for (int i = 0; i < NT; ++i) {
            const int rt = RT0 + i;
            v4f c = *(const v4f*)(trow + rt * 16 + lg * 4);
            c = __builtin_amdgcn_mfma_f32_16x16x32_f16(afrag[i][0], bh0, c, 0, 0, 0);
            c = __builtin_amdgcn_mfma_f32_16x16x32_f16(afrag[i][1], bh1, c, 0, 0, 0);

            // gates arrive pre-scaled: sigm = rcp(1+exp2(x)), tanh from exp2
            float i_ = rcpf(1.f + e2(c[0]));
            float f_ = rcpf(1.f + e2(c[1]));
            float eg = e2(c[2]);
            float g_ = (eg - 1.f) * rcpf(eg + 1.f);
            float o_ = rcpf(1.f + e2(c[3]));
            cs[i] = fmaf(f_, cs[i], (i_ * g_) * K2);   // c kept in 2*log2e domain
            float ec = e2(cs[i]);
            float th = (ec - 1.f) * rcpf(ec + 1.f);
            float hn = o_ * th;

            if (rt != 12 || lg < 2) {                  // folds except pad tile
                wb[i * 4] = (_Float16)hn;
                hcap[i] = cap ? hn : hcap[i];
            }
        }
        __syncthreads();   // h(t) visible to all 4 waves before step t+1
    }

#pragma unroll
    for (int i = 0; i < NT; ++i) {
        const int u = (RT0 + i) * 4 + lg;
        if (u < H) out[seq * 100 + dir * H + u] = hcap[i];
    }
}

__global__ __launch_bounds__(256, 4) void lstm_mfma(
    const int* __restrict__ ids,     // [NSEQ, T]
    const float* __restrict__ tbl,   // [2][VOCAB][ROWS]
    const float* __restrict__ whh_f, // [200][50]
    const float* __restrict__ whh_r, // [200][50]
    float* __restrict__ out)         // [NSEQ, 100]
{
    __shared__ _Float16 hbuf[2][16][56];   // 3584 B, one 16-seq group

    const int tid = threadIdx.x;
    const int lane = tid & 63;
    const int wave = tid >> 6;       // row-quarter: {0-2},{3-5},{6-8},{9-12}
    const int l15 = lane & 15;       // seq within group / C col
    const int lg = lane >> 4;        // k-/row-group
    const int b = blockIdx.x;
    const int dir = b >> 10;         // 2048 blocks: 0..1023 fwd, 1024..2047 rev
    const int seq = (b & 1023) * 16 + l15;

    const float* __restrict__ whh = dir ? whh_r : whh_f;
    const float* __restrict__ tb  = tbl + dir * (VOCAB * ROWS);
    const int* __restrict__ myids = ids + seq * T;

    // zero both h double-buffers (incl. K-pad slots 50..55)
    {
        int* hz = (int*)&hbuf[0][0][0];
#pragma unroll
        for (int i = tid; i < (int)(sizeof(hbuf) / 4); i += 256) hz[i] = 0;
    }

    // ragged length -> capture step (per lane's own sequence)
    int capt;
    {
        const int4* q = (const int4*)myids;
        int4 a0 = q[0], a1 = q[1], a2 = q[2], a3 = q[3];
        int len = (a0.x != 0) + (a0.y != 0) + (a0.z != 0) + (a0.w != 0)
                + (a1.x != 0) + (a1.y != 0) + (a1.z != 0) + (a1.w != 0)
                + (a2.x != 0) + (a2.y != 0) + (a2.z != 0) + (a2.w != 0)
                + (a3.x != 0) + (a3.y != 0) + (a3.z != 0) + (a3.w != 0);
        capt = dir ? (T - 1) : ((len > 1) ? (len - 1) : 0);
    }

    __syncthreads();   // hbuf zeroed

    _Float16* hb0 = &hbuf[0][0][0];
    if      (wave == 0) run_part<0, 3>(whh, tb, myids, hb0, out, seq, dir, capt, l15, lg);
    else if (wave == 1) run_part<3, 3>(whh, tb, myids, hb0, out, seq, dir, capt, l15, lg);
    else if (wave == 2) run_part<6, 3>(whh, tb, myids, hb0, out, seq, dir, capt, l15, lg);
    else                run_part<9, 4>(whh, tb, myids, hb0, out, seq, dir, capt, l15, lg);
}

extern "C" void kernel_launch(void* const* d_in, const int* in_sizes, int n_in,
                              void* d_out, int out_size, void* d_ws, size_t ws_size,
                              hipStream_t stream) {
    const int*   char_ids = (const int*)d_in[0];
    const float* emb      = (const float*)d_in[1];
    const float* w_ih_f   = (const float*)d_in[2];
    const float* w_hh_f   = (const float*)d_in[3];
    const float* b_ih_f   = (const float*)d_in[4];
    const float* b_hh_f   = (const float*)d_in[5];
    const float* w_ih_r   = (const float*)d_in[6];
    const float* w_hh_r   = (const float*)d_in[7];
    const float* b_ih_r   = (const float*)d_in[8];
    const float* b_hh_r   = (const float*)d_in[9];
    float* out = (float*)d_out;
    float* tbl = (float*)d_ws; // [2][VOCAB][ROWS] f32 = 166.4 KB

    const int nt = VOCAB * ROWS; // 20800
    build_tbl<<<(nt + 255) / 256, 256, 0, stream>>>(emb, w_ih_f, b_ih_f, b_hh_f, tbl);
    build_tbl<<<(nt + 255) / 256, 256, 0, stream>>>(emb, w_ih_r, b_ih_r, b_hh_r, tbl + nt);
    // 2048 blocks: 1024 per direction; block = one 16-seq group x 4 row-quarter waves
    lstm_mfma<<<2048, 256, 0, stream>>>(char_ids, tbl, w_hh_f, w_hh_r, out);
}

// Round 9
// 64.578 us; speedup vs baseline: 1.7555x; 1.2374x over previous
//
#include <hip/hip_runtime.h>

#define T 16
#define E 30
#define H 50
#define VOCAB 100
#define ROWS 208        // 13 row-tiles of 16; rows interleaved r = 4*unit + gate
#define K1 1.44269504089f   // log2(e)
#define K2 2.88539008178f   // 2*log2(e)
#define NTILE 13

typedef _Float16 v8hf __attribute__((ext_vector_type(8)));
typedef float v4f __attribute__((ext_vector_type(4)));

extern "C" __device__ float __ocml_native_exp2_f32(float);
__device__ __forceinline__ float e2(float x)   { return __ocml_native_exp2_f32(x); }
__device__ __forceinline__ float rcpf(float x) { return __builtin_amdgcn_rcpf(x); }

// tbl[dir][v][r], r = 4*unit + gate (i,f,g,o), orig row = gate*50+unit.
// Rows pre-scaled: i/f/o by -log2e (sigmoid = rcp(1+exp2(x))), g by 2*log2e.
__global__ void build_tbl(const float* __restrict__ emb,
                          const float* __restrict__ w_ih,
                          const float* __restrict__ b_ih,
                          const float* __restrict__ b_hh,
                          float* __restrict__ tbl) {
    int idx = blockIdx.x * blockDim.x + threadIdx.x;
    if (idx >= VOCAB * ROWS) return;
    int v = idx / ROWS, r = idx % ROWS;
    float s = 0.f;
    if (r < 4 * H) {
        int orig = (r & 3) * H + (r >> 2);
        s = b_ih[orig] + b_hh[orig];
        const float* er = emb + v * E;
        const float* wr = w_ih + orig * E;
#pragma unroll
        for (int e = 0; e < E; ++e) s += er[e] * wr[e];
        s *= ((r & 3) == 2) ? K2 : -K1;
    }
    tbl[idx] = s;
}

// One wave = one 16-seq group, all 13 tiles, zero barriers.
// h LDS layout is READER-packed: hbuf[wave][seg][lane][8] fp16 — the lane's
// B-fragment (k = seg*32 + lg*8 + j, seq = l15) is one conflict-free
// ds_read_b128 at lane*16. Writers scatter b16 (<=4-way, ~free).
__global__ __launch_bounds__(256, 2) void lstm_mfma(
    const int* __restrict__ ids,     // [NSEQ, T]
    const float* __restrict__ tbl,   // [2][VOCAB][ROWS]
    const float* __restrict__ whh_f, // [200][50]
    const float* __restrict__ whh_r, // [200][50]
    float* __restrict__ out)         // [NSEQ, 100]
{
    __shared__ _Float16 hbuf[4][2][64][8];   // 8 KB: [group][seg][lane][8]

    const int tid = threadIdx.x;
    const int lane = tid & 63;
    const int wave = tid >> 6;
    const int l15 = lane & 15;       // seq within group / C col
    const int lg = lane >> 4;        // k-/row-group
    const int b = blockIdx.x;
    const int dir = b >> 8;          // 512 blocks: 0..255 fwd, 256..511 rev
    const int seq = (b & 255) * 64 + wave * 16 + l15;

    const float* __restrict__ whh = dir ? whh_r : whh_f;
    const float* __restrict__ tb  = tbl + dir * (VOCAB * ROWS);
    const int* __restrict__ myids = ids + seq * T;

    _Float16* hb = &hbuf[wave][0][0][0];   // 1024 halves (seg stride 512)

    // zero own group's buffer (wave-private: no barrier needed anywhere)
    {
        int4* z = (int4*)hb;
        int4 zero; zero.x = zero.y = zero.z = zero.w = 0;
        z[lane] = zero;
        z[lane + 64] = zero;
    }

    // ragged length -> capture step (per lane's own sequence)
    int capt;
    {
        const int4* q = (const int4*)myids;
        int4 a0 = q[0], a1 = q[1], a2 = q[2], a3 = q[3];
        int len = (a0.x != 0) + (a0.y != 0) + (a0.z != 0) + (a0.w != 0)
                + (a1.x != 0) + (a1.y != 0) + (a1.z != 0) + (a1.w != 0)
                + (a2.x != 0) + (a2.y != 0) + (a2.z != 0) + (a2.w != 0)
                + (a3.x != 0) + (a3.y != 0) + (a3.z != 0) + (a3.w != 0);
        capt = dir ? (T - 1) : ((len > 1) ? (len - 1) : 0);
    }

    // A-fragments (pre-scaled fp16 W) resident for the whole kernel.
    v8hf afrag[NTILE][2];
#pragma unroll
    for (int i = 0; i < NTILE; ++i) {
        const int r = i * 16 + l15;
        const bool vr = (r < 4 * H);
        const int orig = vr ? ((r & 3) * H + (r >> 2)) : 0;
        const float sc = ((r & 3) == 2) ? K2 : -K1;
#pragma unroll
        for (int kh = 0; kh < 2; ++kh) {
            v8hf af;
#pragma unroll
            for (int j = 0; j < 8; ++j) {
                const int k = kh * 32 + lg * 8 + j;
                af[j] = (_Float16)((vr && k < H) ? sc * whh[orig * H + k] : 0.f);
            }
            afrag[i][kh] = af;
        }
    }

    // per-tile h write offsets (halfwords): unit u = i*4+lg ->
    // [u>>5][((u&31)>>3)*16 + l15][u&7]
    unsigned wa[NTILE];
#pragma unroll
    for (int i = 0; i < NTILE; ++i) {
        const int u = i * 4 + lg;
        wa[i] = ((u >> 5) << 9) + (((u & 31) >> 3) << 7) + (l15 << 3) + (u & 7);
    }
    const _Float16* rb0 = hb + lane * 8;          // seg 0 B-frag
    const _Float16* rb1 = hb + 512 + lane * 8;    // seg 1 B-frag

    float cs[NTILE], hcap[NTILE];
#pragma unroll
    for (int i = 0; i < NTILE; ++i) { cs[i] = 0.f; hcap[i] = 0.f; }

    // prefetch tv for t=0
    v4f tv[NTILE];
    {
        const int id0 = myids[dir ? (T - 1) : 0];
        const float* __restrict__ trow = tb + id0 * ROWS;
#pragma unroll
        for (int i = 0; i < NTILE; ++i)
            tv[i] = *(const v4f*)(trow + i * 16 + lg * 4);
    }

    for (int t = 0; t < T; ++t) {
        // id for step t+1 (issued early; feeds the in-flight prefetch)
        int tn = dir ? (T - 2 - t) : (t + 1);
        if (t == T - 1) tn = dir ? 0 : (T - 1);    // dummy valid index
        const int id_next = myids[tn];
        const float* __restrict__ trow_n = tb + id_next * ROWS;

        // B-fragments: previous step's h (conflict-free b128 reads)
        v8hf bh0 = *(const v8hf*)rb0;
        v8hf bh1 = *(const v8hf*)rb1;

        const bool cap = (t == capt);

#pragma unroll
        for (int i = 0; i < NTILE; ++i) {
            v4f c = __builtin_amdgcn_mfma_f32_16x16x32_f16(afrag[i][0], bh0, tv[i], 0, 0, 0);
            c = __builtin_amdgcn_mfma_f32_16x16x32_f16(afrag[i][1], bh1, c, 0, 0, 0);
            tv[i] = *(const v4f*)(trow_n + i * 16 + lg * 4);   // prefetch t+1

            // gates pre-scaled: sigm = rcp(1+exp2(x)); tanh from exp2
            float i_ = rcpf(1.f + e2(c[0]));
            float f_ = rcpf(1.f + e2(c[1]));
            float eg = e2(c[2]);
            float g_ = (eg - 1.f) * rcpf(eg + 1.f);
            float o_ = rcpf(1.f + e2(c[3]));
            cs[i] = fmaf(f_, cs[i], (i_ * g_) * K2);   // c in 2*log2e domain
            float ec = e2(cs[i]);
            float th = (ec - 1.f) * rcpf(ec + 1.f);
            float hn = o_ * th;

            if (i < 12 || lg < 2) {                    // unit u = i*4+lg < 50
                hb[wa[i]] = (_Float16)hn;
                hcap[i] = cap ? hn : hcap[i];
            }
        }
        // next iteration's rb reads get a compiler lgkmcnt wait on the writes
    }

#pragma unroll
    for (int i = 0; i < NTILE; ++i) {
        const int u = i * 4 + lg;
        if (u < H) out[seq * 100 + dir * H + u] = hcap[i];
    }
}

extern "C" void kernel_launch(void* const* d_in, const int* in_sizes, int n_in,
                              void* d_out, int out_size, void* d_ws, size_t ws_size,
                              hipStream_t stream) {
    const int*   char_ids = (const int*)d_in[0];
    const float* emb      = (const float*)d_in[1];
    const float* w_ih_f   = (const float*)d_in[2];
    const float* w_hh_f   = (const float*)d_in[3];
    const float* b_ih_f   = (const float*)d_in[4];
    const float* b_hh_f   = (const float*)d_in[5];
    const float* w_ih_r   = (const float*)d_in[6];
    const float* w_hh_r   = (const float*)d_in[7];
    const float* b_ih_r   = (const float*)d_in[8];
    const float* b_hh_r   = (const float*)d_in[9];
    float* out = (float*)d_out;
    float* tbl = (float*)d_ws; // [2][VOCAB][ROWS] f32 = 166.4 KB

    const int nt = VOCAB * ROWS; // 20800
    build_tbl<<<(nt + 255) / 256, 256, 0, stream>>>(emb, w_ih_f, b_ih_f, b_hh_f, tbl);
    build_tbl<<<(nt + 255) / 256, 256, 0, stream>>>(emb, w_ih_r, b_ih_r, b_hh_r, tbl + nt);
    // 512 blocks: 256 per direction; block = 4 independent 16-seq waves
    lstm_mfma<<<512, 256, 0, stream>>>(char_ids, tbl, w_hh_f, w_hh_r, out);
}